// Round 8
// baseline (576.996 us; speedup 1.0000x reference)
//
#include <hip/hip_runtime.h>

typedef _Float16 hh;
typedef _Float16 h2  __attribute__((ext_vector_type(2)));
typedef _Float16 v4h __attribute__((ext_vector_type(4)));
typedef _Float16 v8h __attribute__((ext_vector_type(8)));
typedef float v4f    __attribute__((ext_vector_type(4)));
typedef unsigned short u16;

#define T_STEPS 36
#define FEAT 9
#define HID 64
// BT=16, grid=1024, 4 blocks/CU (launch_bounds 256,4): the R1 geometry that
// previously exploded traffic. This round decouples ALL global IO from step
// cadence (4-step float4-aligned slab staging in + LDS-buffered line flush
// out), so traffic should stay at the clean ~34/23 MB while waves/SIMD double.
#define BT 16
// sIn row (halves, stride 232): parity0 @0 [c_c 0..8|m 9..17|h 18..81|1@82],
// parity1 @96 same (+96, one@178), dA @192..200, dB @202..210, 1@212.
#define SIN_STR 232
// packed per-element row (halves): x 0..8 | m 9..17 | xh 18..26 | gx 27..35
#define PK_STR 40

__device__ __forceinline__ float fast_exp2(float x) {
#if __has_builtin(__builtin_amdgcn_exp2f)
  return __builtin_amdgcn_exp2f(x);
#else
  return exp2f(x);
#endif
}
__device__ __forceinline__ float fast_rcp(float x) {
#if __has_builtin(__builtin_amdgcn_rcpf)
  return __builtin_amdgcn_rcpf(x);
#else
  return 1.f / x;
#endif
}
__device__ __forceinline__ float sigmoid_fast(float x) {
  return fast_rcp(1.f + fast_exp2(x * -1.442695041f));
}
__device__ __forceinline__ float tanh_fast(float x) {
  return 1.f - 2.f * fast_rcp(1.f + fast_exp2(x * 2.885390082f));
}
__device__ __forceinline__ float fdot2(h2 a, h2 b, float c) {
#if __has_builtin(__builtin_amdgcn_fdot2)
  return __builtin_amdgcn_fdot2(a, b, c, false);
#else
  return c + (float)a[0] * (float)b[0] + (float)a[1] * (float)b[1];
#endif
}
__device__ __forceinline__ h2 mkh2(hh a, hh b) { h2 r; r[0] = a; r[1] = b; return r; }
__device__ __forceinline__ v4f mfma16(v8h a, v8h b, v4f c) {
  return __builtin_amdgcn_mfma_f32_16x16x32_f16(a, b, c, 0, 0, 0);
}

// ---------------- fallback kernel 0: zero ws denom slots + loss slot -------
__global__ void zero_ws(float* __restrict__ ws, float* __restrict__ out) {
  int tid = threadIdx.x;
  if (tid < T_STEPS) ws[tid] = 0.f;
  if (tid == 0) out[0] = 0.f;
}

// ---- fallback kernel 1: denom via global atomics (old path) ----
__global__ __launch_bounds__(256) void denom_kernel(const float* __restrict__ masks,
                                                    float* __restrict__ ws) {
  __shared__ float red[T_STEPS];
  const int tid = threadIdx.x;
  if (tid < T_STEPS) red[tid] = 0.f;
  __syncthreads();
  const int idx = blockIdx.x * 256 + tid;
  const int t0 = (idx % 9) * 4;
  const float4* p = (const float4*)masks + (size_t)idx * 9;
  float acc[4] = {0.f, 0.f, 0.f, 0.f};
#pragma unroll
  for (int c = 0; c < 9; ++c) {
    float4 v = p[c];
    acc[(4 * c) / 9]     += v.x;
    acc[(4 * c + 1) / 9] += v.y;
    acc[(4 * c + 2) / 9] += v.z;
    acc[(4 * c + 3) / 9] += v.w;
  }
#pragma unroll
  for (int j = 0; j < 4; ++j) atomicAdd(&red[t0 + j], acc[j]);
  __syncthreads();
  if (tid < T_STEPS) atomicAdd(&ws[tid], red[tid]);
}

// ---- kernel 1a: per-block denom partials, NO global atomics (R7, proven) --
__global__ __launch_bounds__(256) void denom_part(const float* __restrict__ masks,
                                                  float* __restrict__ ws) {
  __shared__ float red[T_STEPS];
  const int tid = threadIdx.x;
  if (tid < T_STEPS) red[tid] = 0.f;
  __syncthreads();
  const int idx = blockIdx.x * 256 + tid;
  const int t0 = (idx % 9) * 4;
  const float4* p = (const float4*)masks + (size_t)idx * 9;
  float acc[4] = {0.f, 0.f, 0.f, 0.f};
#pragma unroll
  for (int c = 0; c < 9; ++c) {
    float4 v = p[c];
    acc[(4 * c) / 9]     += v.x;
    acc[(4 * c + 1) / 9] += v.y;
    acc[(4 * c + 2) / 9] += v.z;
    acc[(4 * c + 3) / 9] += v.w;
  }
#pragma unroll
  for (int j = 0; j < 4; ++j) atomicAdd(&red[t0 + j], acc[j]);   // LDS only
  __syncthreads();
  if (tid < T_STEPS) ws[64 + blockIdx.x * T_STEPS + tid] = red[tid];
}

// ---- kernel 1b: final reduce, writes ws[t], zeroes out[0] (R7, proven) ----
__global__ __launch_bounds__(576) void denom_final(float* __restrict__ ws,
                                                   float* __restrict__ out,
                                                   int nblocks) {
  __shared__ float red[576];
  const int tid = threadIdx.x;
  const int t = tid >> 4;
  const int l = tid & 15;
  float s = 0.f;
  for (int b = l; b < nblocks; b += 16) s += ws[64 + b * T_STEPS + t];
  red[tid] = s;
  __syncthreads();
  if (l < 8) red[tid] += red[tid + 8];
  __syncthreads();
  if (l < 4) red[tid] += red[tid + 4];
  __syncthreads();
  if (l < 2) red[tid] += red[tid + 2];
  __syncthreads();
  if (l == 0) ws[t] = red[tid] + red[tid + 1];
  if (tid == 0) out[0] = 0.f;
}

// Raw barrier: LDS ordering only; global loads/stores stay in flight.
#define BARX() asm volatile("s_waitcnt lgkmcnt(0)\n\ts_barrier" ::: "memory")

// ---------------- kernel 2: the full RITS scan (slab-staged IO) ------------
__global__ __launch_bounds__(256, 4) void rits_kernel(
    const float* __restrict__ values, const float* __restrict__ masks,
    const float* __restrict__ deltas,
    const float* __restrict__ W_gh, const float* __restrict__ b_gh,
    const float* __restrict__ W_gx, const float* __restrict__ b_gx,
    const float* __restrict__ W_hist, const float* __restrict__ b_hist,
    const float* __restrict__ W_feat, const float* __restrict__ b_feat,
    const float* __restrict__ W_comb, const float* __restrict__ b_comb,
    const float* __restrict__ W_ih, const float* __restrict__ W_hh,
    const float* __restrict__ b_ih, const float* __restrict__ b_hh,
    const float* __restrict__ denom, float* __restrict__ out) {

  __shared__ __align__(16) hh sIn[BT * SIN_STR];   // 7424 B
  __shared__ __align__(16) hh sPk[BT * PK_STR];    // 1280 B
  __shared__ __align__(16) hh sX[2][BT][36];       // 4-step input slabs (dbuf)
  __shared__ __align__(16) hh sM[2][BT][36];
  __shared__ __align__(16) hh sD[2][BT][36];
  __shared__ __align__(16) float sOut[BT][36];     // 4-step output buffer
  __shared__ float sRed[256];

  const int tid = threadIdx.x;
  const int lane = tid & 63;
  const int wid = tid >> 6;
  const int q = lane >> 4;
  const int nlo = lane & 15;
  const int b0 = blockIdx.x * BT;
  const int j_col = 16 * wid + nlo;

  // ---- persistent register B-fragments ----
  v8h bG[4][3];        // gates: k0..17 Wih, 18..81 Whh, 82 bias; cols 64p+j_col
#pragma unroll
  for (int p = 0; p < 4; ++p)
#pragma unroll
    for (int kt = 0; kt < 3; ++kt) {
      int n = 64 * p + j_col;
      v8h r;
#pragma unroll
      for (int jj = 0; jj < 8; ++jj) {
        int k = kt * 32 + q * 8 + jj;
        float v = 0.f;
        if (k < 18)       v = W_ih[n * 18 + k];
        else if (k < 82)  v = W_hh[n * 64 + (k - 18)];
        else if (k == 82) v = b_ih[n] + b_hh[n];
        r[jj] = (hh)v;
      }
      bG[p][kt] = r;
    }
  v8h bH[3];           // x_h: cols nlo<9, k 18..81 Whist, 82 bias
#pragma unroll
  for (int kt = 0; kt < 3; ++kt) {
    v8h r;
#pragma unroll
    for (int jj = 0; jj < 8; ++jj) {
      int k = kt * 32 + q * 8 + jj;
      float v = 0.f;
      if (nlo < 9) {
        if (k >= 18 && k < 82) v = W_hist[nlo * 64 + (k - 18)];
        else if (k == 82)      v = b_hist[nlo];
      }
      r[jj] = (hh)v;
    }
    bH[kt] = r;
  }
  // gamma_h windows: A @176 (bias@k2->178, dA k16..24); B @200 (dB k2..10, 1@k12)
  v8h bGamA, bGamB;
  {
    int n = j_col;
    v8h ra, rb;
#pragma unroll
    for (int jj = 0; jj < 8; ++jj) {
      int k = q * 8 + jj;
      float va = 0.f, vb = 0.f;
      if (k == 2) va = b_gh[n];
      else if (k >= 16 && k < 25) va = W_gh[n * 9 + (k - 16)];
      if (k >= 2 && k < 11) vb = W_gh[n * 9 + (k - 2)];
      else if (k == 12) vb = b_gh[n];
      ra[jj] = (hh)va; rb[jj] = (hh)vb;
    }
    bGamA = ra; bGamB = rb;
  }

  // ---- per-lane P2 weights (element eP = tid>>3 < 16, feature fqw) ----
  const int eP = tid >> 3, fqw = tid & 7;
  h2 wf1[5], wf2[5], wc1[9], wc2[9];
  float bf1 = b_feat[fqw], bf2 = b_feat[8];
  float bc1v = b_comb[fqw], bc2v = b_comb[8];
#pragma unroll
  for (int j = 0; j < 5; ++j) {
    int i0 = 2 * j, i1 = 2 * j + 1;
    hh a0 = (hh)((i0 == fqw) ? 0.f : W_feat[fqw * 9 + i0]);
    hh a1 = (hh)((i1 < 9) ? ((i1 == fqw) ? 0.f : W_feat[fqw * 9 + i1]) : 0.f);
    wf1[j] = mkh2(a0, a1);
    hh c0 = (hh)((i0 == 8) ? 0.f : W_feat[8 * 9 + i0]);
    hh c1 = (hh)((i1 < 9) ? W_feat[8 * 9 + i1] : 0.f);
    wf2[j] = mkh2(c0, c1);
  }
#pragma unroll
  for (int j = 0; j < 9; ++j) {
    wc1[j] = mkh2((hh)W_comb[fqw * 18 + 2 * j], (hh)W_comb[fqw * 18 + 2 * j + 1]);
    wc2[j] = mkh2((hh)W_comb[8 * 18 + 2 * j], (hh)W_comb[8 * 18 + 2 * j + 1]);
  }

  // ---- loader mapping: 144 threads, dual role: (e1, chunk f1) for slab
  //      float4 IO, (e1, feature f1) for per-step commits ----
  const bool ldr = (tid < 9 * BT);
  const int e1 = tid / 9, f1 = tid - 9 * e1;
  const float wgx1 = W_gx[f1 * 9 + f1], bgx1 = b_gx[f1];

  // ---- LDS init ----
  for (int i = tid; i < BT * SIN_STR; i += 256) sIn[i] = (hh)0.f;
  __syncthreads();
  if (tid < BT) {
    sIn[tid * SIN_STR + 82] = (hh)1.f;
    sIn[tid * SIN_STR + 178] = (hh)1.f;
    sIn[tid * SIN_STR + 212] = (hh)1.f;
  }

  // ---- bootstrap: slabs 0,1 (t=0..7) synchronously into staging ----
  float4 vX = {0,0,0,0}, vM = {0,0,0,0}, vD = {0,0,0,0};   // in-flight slab regs
  if (ldr) {
    const float* vb = values + (size_t)(b0 + e1) * (T_STEPS * FEAT);
    const float* mb = masks  + (size_t)(b0 + e1) * (T_STEPS * FEAT);
    const float* db = deltas + (size_t)(b0 + e1) * (T_STEPS * FEAT);
#pragma unroll
    for (int s = 0; s < 2; ++s) {
      float4 x4 = *(const float4*)(vb + s * 36 + f1 * 4);
      float4 m4 = *(const float4*)(mb + s * 36 + f1 * 4);
      float4 d4 = *(const float4*)(db + s * 36 + f1 * 4);
      sX[s][e1][f1 * 4 + 0] = (hh)x4.x; sX[s][e1][f1 * 4 + 1] = (hh)x4.y;
      sX[s][e1][f1 * 4 + 2] = (hh)x4.z; sX[s][e1][f1 * 4 + 3] = (hh)x4.w;
      sM[s][e1][f1 * 4 + 0] = (hh)m4.x; sM[s][e1][f1 * 4 + 1] = (hh)m4.y;
      sM[s][e1][f1 * 4 + 2] = (hh)m4.z; sM[s][e1][f1 * 4 + 3] = (hh)m4.w;
      sD[s][e1][f1 * 4 + 0] = (hh)d4.x; sD[s][e1][f1 * 4 + 1] = (hh)d4.y;
      sD[s][e1][f1 * 4 + 2] = (hh)d4.z; sD[s][e1][f1 * 4 + 3] = (hh)d4.w;
    }
  }
  __syncthreads();
  // initial t=0 commits (feature role)
  if (ldr) {
    sPk[e1 * PK_STR + f1]     = sX[0][e1][f1];
    sPk[e1 * PK_STR + 9 + f1] = sM[0][e1][f1];
    float d0 = (float)sD[0][e1][f1];
    sPk[e1 * PK_STR + 27 + f1] =
        (hh)fast_exp2(fmaxf(d0 * wgx1 + bgx1, 0.f) * -1.442695041f);
    sIn[e1 * SIN_STR + 202 + f1] = sD[0][e1][9 + f1];   // d(1) -> dB (parity 1)
  }
  __syncthreads();

  float c_s[4];
#pragma unroll
  for (int i = 0; i < 4; ++i) c_s[i] = 0.f;
  float loss_acc = 0.f;

  for (int t = 0; t < T_STEPS; ++t) {
    const float inv_den = fast_rcp(denom[t] + 1e-5f);
    const int pb = (t & 1) * 96;
    const int pub = 96 - pb;

    // ==== Phase A: gamma(t+1) MFMA + wave-local x_h MFMA -> P2 ====
    v4f gacc;
    {
      const int sel = (t + 1) & 1;
      const int awin = 176 + sel * 24;
      v8h ag = *(const v8h*)&sIn[nlo * SIN_STR + awin + q * 8];
      v4f z4 = {0.f, 0.f, 0.f, 0.f};
      gacc = sel ? mfma16(ag, bGamB, z4) : mfma16(ag, bGamA, z4);
    }
    if (wid < 2) {     // waves 0,1 own the 16 P2 elements (8 each)
      v4f xacc = {0.f, 0.f, 0.f, 0.f};
#pragma unroll
      for (int kt = 0; kt < 3; ++kt) {
        v8h a_ = *(const v8h*)&sIn[nlo * SIN_STR + pb + kt * 32 + q * 8];
        xacc = mfma16(a_, bH[kt], xacc);
      }
      // wave0 -> rows 0..7 (q 0,1), wave1 -> rows 8..15 (q 2,3)
      if ((q >> 1) == wid && nlo < 9) {
#pragma unroll
        for (int r = 0; r < 4; ++r)
          sPk[(q * 4 + r) * PK_STR + 18 + nlo] = (hh)xacc[r];
      }
    }
    asm volatile("s_waitcnt lgkmcnt(0)" ::: "memory");   // wave-local fence

    if (eP < BT) {     // P2: tid<128 (waves 0,1)
      const int pk = eP * PK_STR;
      float x_f  = (float)sPk[pk + fqw];
      float m_f  = (float)sPk[pk + 9 + fqw];
      float xh_f = (float)sPk[pk + 18 + fqw];
      v8h r0 = *(const v8h*)&sPk[pk];
      v8h r1 = *(const v8h*)&sPk[pk + 8];
      v8h r2 = *(const v8h*)&sPk[pk + 16];
      v8h r3 = *(const v8h*)&sPk[pk + 24];
      v4h r4 = *(const v4h*)&sPk[pk + 32];
      hh xxh[9] = {r0[0],r0[1],r0[2],r0[3],r0[4],r0[5],r0[6],r0[7],r1[0]};
      hh mmh[9] = {r1[1],r1[2],r1[3],r1[4],r1[5],r1[6],r1[7],r2[0],r2[1]};
      hh xhh[9] = {r2[2],r2[3],r2[4],r2[5],r2[6],r2[7],r3[0],r3[1],r3[2]};
      hh gxh[9] = {r3[3],r3[4],r3[5],r3[6],r3[7],r4[0],r4[1],r4[2],r4[3]};
      hh xch[10];
#pragma unroll
      for (int f = 0; f < 9; ++f) {
        u16 mb = __builtin_bit_cast(u16, mmh[f]);
        xch[f] = mb ? xxh[f] : xhh[f];
      }
      xch[9] = (hh)0.f;
      h2 xc2[5] = {mkh2(xch[0],xch[1]), mkh2(xch[2],xch[3]), mkh2(xch[4],xch[5]),
                   mkh2(xch[6],xch[7]), mkh2(xch[8],xch[9])};
      h2 g2[9]  = {mkh2(gxh[0],gxh[1]), mkh2(gxh[2],gxh[3]), mkh2(gxh[4],gxh[5]),
                   mkh2(gxh[6],gxh[7]), mkh2(gxh[8],mmh[0]), mkh2(mmh[1],mmh[2]),
                   mkh2(mmh[3],mmh[4]), mkh2(mmh[5],mmh[6]), mkh2(mmh[7],mmh[8])};
      float z1a = bf1, z1b = 0.f;
      z1a = fdot2(wf1[0], xc2[0], z1a); z1b = fdot2(wf1[1], xc2[1], z1b);
      z1a = fdot2(wf1[2], xc2[2], z1a); z1b = fdot2(wf1[3], xc2[3], z1b);
      z1a = fdot2(wf1[4], xc2[4], z1a);
      float z1 = z1a + z1b;
      float a1a = bc1v, a1b = 0.f, a1c = 0.f;
      a1a = fdot2(wc1[0], g2[0], a1a); a1b = fdot2(wc1[1], g2[1], a1b);
      a1c = fdot2(wc1[2], g2[2], a1c); a1a = fdot2(wc1[3], g2[3], a1a);
      a1b = fdot2(wc1[4], g2[4], a1b); a1c = fdot2(wc1[5], g2[5], a1c);
      a1a = fdot2(wc1[6], g2[6], a1a); a1b = fdot2(wc1[7], g2[7], a1b);
      a1c = fdot2(wc1[8], g2[8], a1c);
      float a1 = (a1a + a1b) + a1c;
      float ch1 = xh_f + a1 * (z1 - xh_f);
      bool obs1 = (m_f != 0.f);
      float cc1 = obs1 ? x_f : ch1;
      float lterm = obs1 ? (fabsf(x_f - xh_f) + fabsf(x_f - z1) + fabsf(x_f - ch1)) : 0.f;
      sIn[eP * SIN_STR + pb + fqw] = (hh)cc1;
      sIn[eP * SIN_STR + pb + 9 + fqw] = (hh)m_f;
      sOut[eP][(t & 3) * 9 + fqw] = cc1;          // buffered; flushed every 4 steps
      if (fqw == 7) {
        float z2a = bf2, z2b = 0.f;
        z2a = fdot2(wf2[0], xc2[0], z2a); z2b = fdot2(wf2[1], xc2[1], z2b);
        z2a = fdot2(wf2[2], xc2[2], z2a); z2b = fdot2(wf2[3], xc2[3], z2b);
        z2a = fdot2(wf2[4], xc2[4], z2a);
        float z2 = z2a + z2b;
        float a2a = bc2v, a2b = 0.f, a2c = 0.f;
        a2a = fdot2(wc2[0], g2[0], a2a); a2b = fdot2(wc2[1], g2[1], a2b);
        a2c = fdot2(wc2[2], g2[2], a2c); a2a = fdot2(wc2[3], g2[3], a2a);
        a2b = fdot2(wc2[4], g2[4], a2b); a2c = fdot2(wc2[5], g2[5], a2c);
        a2a = fdot2(wc2[6], g2[6], a2a); a2b = fdot2(wc2[7], g2[7], a2b);
        a2c = fdot2(wc2[8], g2[8], a2c);
        float a2 = (a2a + a2b) + a2c;
        float x8 = (float)xxh[8], m8 = (float)mmh[8], xh8 = (float)xhh[8];
        float ch2 = xh8 + a2 * (z2 - xh8);
        bool obs2 = (m8 != 0.f);
        float cc2 = obs2 ? x8 : ch2;
        lterm += obs2 ? (fabsf(x8 - xh8) + fabsf(x8 - z2) + fabsf(x8 - ch2)) : 0.f;
        sIn[eP * SIN_STR + pb + 8] = (hh)cc2;
        sIn[eP * SIN_STR + pb + 17] = mmh[8];
        sOut[eP][(t & 3) * 9 + 8] = cc2;
      }
      loss_acc += lterm * inv_den;
    }
    BARX();

    // ==== Phase B: slab issue, gates MFMA, LSTM, publish h, commits ====
    {
      // issue slab (t/4)+2 global loads (float4-aligned full lines)
      if (ldr && (t & 3) == 0 && t <= 4 * (T_STEPS / 4 - 3)) {   // t <= 24
        size_t base = (size_t)(b0 + e1) * (T_STEPS * FEAT) + (t + 8) * FEAT + f1 * 4;
        vX = *(const float4*)(values + base);
        vM = *(const float4*)(masks + base);
        vD = *(const float4*)(deltas + base);
      }

      v8h af[3];
#pragma unroll
      for (int kt = 0; kt < 3; ++kt)
        af[kt] = *(const v8h*)&sIn[nlo * SIN_STR + pb + kt * 32 + q * 8];
      v4f acc[4];
#pragma unroll
      for (int p = 0; p < 4; ++p) acc[p] = (v4f){0.f, 0.f, 0.f, 0.f};
#pragma unroll
      for (int p = 0; p < 4; ++p)
#pragma unroll
        for (int kt = 0; kt < 3; ++kt)
          acc[p] = mfma16(af[kt], bG[p][kt], acc[p]);
#pragma unroll
      for (int r = 0; r < 4; ++r) {
        float ig = sigmoid_fast(acc[0][r]);
        float fg = sigmoid_fast(acc[1][r]);
        float gg = tanh_fast(acc[2][r]);
        float og = sigmoid_fast(acc[3][r]);
        float cn = fg * c_s[r] + ig * gg;
        c_s[r] = cn;
        float hn = og * tanh_fast(cn);
        float gam = fast_exp2(fmaxf(gacc[r], 0.f) * -1.442695041f);
        sIn[(q * 4 + r) * SIN_STR + pub + 18 + j_col] = (hh)(hn * gam);
      }

      if (ldr) {
        if (t + 1 < T_STEPS) {     // commit t+1 inputs from staging (feature role)
          const int s1 = ((t + 1) >> 2) & 1, o1 = ((t + 1) & 3) * 9;
          sPk[e1 * PK_STR + f1]     = sX[s1][e1][o1 + f1];
          sPk[e1 * PK_STR + 9 + f1] = sM[s1][e1][o1 + f1];
          float d1 = (float)sD[s1][e1][o1 + f1];
          sPk[e1 * PK_STR + 27 + f1] =
              (hh)fast_exp2(fmaxf(d1 * wgx1 + bgx1, 0.f) * -1.442695041f);
        }
        if (t + 2 < T_STEPS) {     // stage d(t+2) into gamma window
          const int s2 = ((t + 2) >> 2) & 1, o2 = ((t + 2) & 3) * 9;
          sIn[e1 * SIN_STR + 192 + (t & 1) * 10 + f1] = sD[s2][e1][o2 + f1];
        }
        if ((t & 3) == 3) {
          if (t < T_STEPS - 8) {   // commit slab regs -> staging buf (t>>2)&1
            const int buf = (t >> 2) & 1;
            sX[buf][e1][f1 * 4 + 0] = (hh)vX.x; sX[buf][e1][f1 * 4 + 1] = (hh)vX.y;
            sX[buf][e1][f1 * 4 + 2] = (hh)vX.z; sX[buf][e1][f1 * 4 + 3] = (hh)vX.w;
            sM[buf][e1][f1 * 4 + 0] = (hh)vM.x; sM[buf][e1][f1 * 4 + 1] = (hh)vM.y;
            sM[buf][e1][f1 * 4 + 2] = (hh)vM.z; sM[buf][e1][f1 * 4 + 3] = (hh)vM.w;
            sD[buf][e1][f1 * 4 + 0] = (hh)vD.x; sD[buf][e1][f1 * 4 + 1] = (hh)vD.y;
            sD[buf][e1][f1 * 4 + 2] = (hh)vD.z; sD[buf][e1][f1 * 4 + 3] = (hh)vD.w;
          }
          // flush 4-step output slab: 144 B/elem contiguous (scalar: +1 offset
          // in out breaks 16B alignment)
          size_t ob = 1 + (size_t)(b0 + e1) * (T_STEPS * FEAT) +
                      (size_t)(t - 3) * FEAT + f1 * 4;
          out[ob + 0] = sOut[e1][f1 * 4 + 0];
          out[ob + 1] = sOut[e1][f1 * 4 + 1];
          out[ob + 2] = sOut[e1][f1 * 4 + 2];
          out[ob + 3] = sOut[e1][f1 * 4 + 3];
        }
      }
    }
    BARX();
  }

  // ---- loss reduction ----
  sRed[tid] = loss_acc;
  __syncthreads();
  for (int k = 128; k > 0; k >>= 1) {
    if (tid < k) sRed[tid] += sRed[tid + k];
    __syncthreads();
  }
  if (tid == 0) atomicAdd(out, sRed[0] * (1.f / (float)T_STEPS));
}

extern "C" void kernel_launch(void* const* d_in, const int* in_sizes, int n_in,
                              void* d_out, int out_size, void* d_ws, size_t ws_size,
                              hipStream_t stream) {
  const float* values = (const float*)d_in[0];
  const float* masks  = (const float*)d_in[1];
  const float* deltas = (const float*)d_in[2];
  const float* W_gh   = (const float*)d_in[3];
  const float* b_gh   = (const float*)d_in[4];
  const float* W_gx   = (const float*)d_in[5];
  const float* b_gx   = (const float*)d_in[6];
  const float* W_hist = (const float*)d_in[7];
  const float* b_hist = (const float*)d_in[8];
  const float* W_feat = (const float*)d_in[9];
  const float* b_feat = (const float*)d_in[10];
  const float* W_comb = (const float*)d_in[11];
  const float* b_comb = (const float*)d_in[12];
  const float* W_ih   = (const float*)d_in[13];
  const float* W_hh   = (const float*)d_in[14];
  const float* b_ih   = (const float*)d_in[15];
  const float* b_hh   = (const float*)d_in[16];

  float* out = (float*)d_out;
  float* ws  = (float*)d_ws;
  int B = in_sizes[0] / (T_STEPS * FEAT);
  int nb1 = (B * 9) / 256;

  size_t need = (size_t)(64 + (size_t)nb1 * T_STEPS) * sizeof(float);
  if (ws_size >= need) {
    denom_part<<<nb1, 256, 0, stream>>>(masks, ws);
    denom_final<<<1, 576, 0, stream>>>(ws, out, nb1);
  } else {
    zero_ws<<<1, 64, 0, stream>>>(ws, out);
    denom_kernel<<<nb1, 256, 0, stream>>>(masks, ws);
  }
  rits_kernel<<<B / BT, 256, 0, stream>>>(values, masks, deltas,
                                          W_gh, b_gh, W_gx, b_gx,
                                          W_hist, b_hist, W_feat, b_feat,
                                          W_comb, b_comb, W_ih, W_hh,
                                          b_ih, b_hh, ws, out);
}

// Round 9
// 245.307 us; speedup vs baseline: 2.3521x; 2.3521x over previous
//
#include <hip/hip_runtime.h>

typedef _Float16 hh;
typedef _Float16 h2  __attribute__((ext_vector_type(2)));
typedef _Float16 v4h __attribute__((ext_vector_type(4)));
typedef _Float16 v8h __attribute__((ext_vector_type(8)));
typedef float v4f    __attribute__((ext_vector_type(4)));
typedef unsigned short u16;

#define T_STEPS 36
#define FEAT 9
#define HID 64
#define BT 32
// sIn row (halves, stride 264 = 132 words; 132*{0..7} mod 32 = {0,4,..,28}
// distinct -> b128 A-frag reads conflict-free (rows r/r+8 alias 2-way = free)):
//   parity0 block @0:   [c_c 0..8 | m 9..17 | h 18..81 | 1 @82 | 0 @83..95]
//   parity1 block @96:  same layout +96 (bias one @178)
//   dA @192..200 | 0 @201 | dB @202..210 | 0 @211 | 1 @212 | 0 @213..231
//   ALPHA window @232: [1 @232 | gx(t) 233..241 | m(t) 242..250 | 0 ..263]
#define SIN_STR 264
// packed per-element row (halves): x 0..8 | m 9..17 | xh 18..26 | alpha 27..35
// (alpha = W_comb@[gx;m]+b_comb, computed by the Phase-A MFMA, NOT in P2)
#define PK_STR 40

__device__ __forceinline__ float fast_exp2(float x) {
#if __has_builtin(__builtin_amdgcn_exp2f)
  return __builtin_amdgcn_exp2f(x);
#else
  return exp2f(x);
#endif
}
__device__ __forceinline__ float fast_rcp(float x) {
#if __has_builtin(__builtin_amdgcn_rcpf)
  return __builtin_amdgcn_rcpf(x);
#else
  return 1.f / x;
#endif
}
__device__ __forceinline__ float sigmoid_fast(float x) {
  return fast_rcp(1.f + fast_exp2(x * -1.442695041f));
}
__device__ __forceinline__ float tanh_fast(float x) {
  return 1.f - 2.f * fast_rcp(1.f + fast_exp2(x * 2.885390082f));
}
__device__ __forceinline__ float fdot2(h2 a, h2 b, float c) {
#if __has_builtin(__builtin_amdgcn_fdot2)
  return __builtin_amdgcn_fdot2(a, b, c, false);
#else
  return c + (float)a[0] * (float)b[0] + (float)a[1] * (float)b[1];
#endif
}
__device__ __forceinline__ h2 mkh2(hh a, hh b) { h2 r; r[0] = a; r[1] = b; return r; }
__device__ __forceinline__ v4f mfma16(v8h a, v8h b, v4f c) {
  return __builtin_amdgcn_mfma_f32_16x16x32_f16(a, b, c, 0, 0, 0);
}

// ---------------- fallback kernel 0: zero ws denom slots + loss slot -------
__global__ void zero_ws(float* __restrict__ ws, float* __restrict__ out) {
  int tid = threadIdx.x;
  if (tid < T_STEPS) ws[tid] = 0.f;
  if (tid == 0) out[0] = 0.f;
}

// ---- fallback kernel 1: denom via global atomics (old path) ----
__global__ __launch_bounds__(256) void denom_kernel(const float* __restrict__ masks,
                                                    float* __restrict__ ws) {
  __shared__ float red[T_STEPS];
  const int tid = threadIdx.x;
  if (tid < T_STEPS) red[tid] = 0.f;
  __syncthreads();
  const int idx = blockIdx.x * 256 + tid;
  const int t0 = (idx % 9) * 4;
  const float4* p = (const float4*)masks + (size_t)idx * 9;
  float acc[4] = {0.f, 0.f, 0.f, 0.f};
#pragma unroll
  for (int c = 0; c < 9; ++c) {
    float4 v = p[c];
    acc[(4 * c) / 9]     += v.x;
    acc[(4 * c + 1) / 9] += v.y;
    acc[(4 * c + 2) / 9] += v.z;
    acc[(4 * c + 3) / 9] += v.w;
  }
#pragma unroll
  for (int j = 0; j < 4; ++j) atomicAdd(&red[t0 + j], acc[j]);
  __syncthreads();
  if (tid < T_STEPS) atomicAdd(&ws[tid], red[tid]);
}

// ---- kernel 1a: per-block denom partials, NO global atomics (R7, proven) --
__global__ __launch_bounds__(256) void denom_part(const float* __restrict__ masks,
                                                  float* __restrict__ ws) {
  __shared__ float red[T_STEPS];
  const int tid = threadIdx.x;
  if (tid < T_STEPS) red[tid] = 0.f;
  __syncthreads();
  const int idx = blockIdx.x * 256 + tid;
  const int t0 = (idx % 9) * 4;
  const float4* p = (const float4*)masks + (size_t)idx * 9;
  float acc[4] = {0.f, 0.f, 0.f, 0.f};
#pragma unroll
  for (int c = 0; c < 9; ++c) {
    float4 v = p[c];
    acc[(4 * c) / 9]     += v.x;
    acc[(4 * c + 1) / 9] += v.y;
    acc[(4 * c + 2) / 9] += v.z;
    acc[(4 * c + 3) / 9] += v.w;
  }
#pragma unroll
  for (int j = 0; j < 4; ++j) atomicAdd(&red[t0 + j], acc[j]);   // LDS only
  __syncthreads();
  if (tid < T_STEPS) ws[64 + blockIdx.x * T_STEPS + tid] = red[tid];
}

// ---- kernel 1b: final reduce, writes ws[t], zeroes out[0] (R7, proven) ----
__global__ __launch_bounds__(576) void denom_final(float* __restrict__ ws,
                                                   float* __restrict__ out,
                                                   int nblocks) {
  __shared__ float red[576];
  const int tid = threadIdx.x;
  const int t = tid >> 4;
  const int l = tid & 15;
  float s = 0.f;
  for (int b = l; b < nblocks; b += 16) s += ws[64 + b * T_STEPS + t];
  red[tid] = s;
  __syncthreads();
  if (l < 8) red[tid] += red[tid + 8];
  __syncthreads();
  if (l < 4) red[tid] += red[tid + 4];
  __syncthreads();
  if (l < 2) red[tid] += red[tid + 2];
  __syncthreads();
  if (l == 0) ws[t] = red[tid] + red[tid + 1];
  if (tid == 0) out[0] = 0.f;
}

// Raw barrier: LDS ordering only; global loads/stores stay in flight.
#define BARX() asm volatile("s_waitcnt lgkmcnt(0)\n\ts_barrier" ::: "memory")

// One RITS timestep, 2 barriers (R4 structure + alpha-MFMA):
//  Phase A: gamma(t+1) MFMA + alpha(t) MFMA + wave-local x_h MFMA (wave writes
//           its own 8 rows' xh AND alpha to sPk) -> wave-local fence -> P2.
//  Phase B: gates MFMA + LSTM + publish h + loader commits (x,m->sPk;
//           gx,m->ALPHA window) + issue next-step global loads.
#define RITS_STEP(t, pxC,pmC,pdC,pxCb,pmCb,pdCb, pxN,pmN,pdN,pxNb,pmNb,pdNb)   \
  {                                                                            \
    const float inv_den = fast_rcp(denom[(t)] + 1e-5f);                        \
    const int pb = ((t) & 1) * 96;                                             \
    /* ---- gamma(t+1)-arg MFMA (all rows, both tiles; used in Phase B) */     \
    v4f gacc[2];                                                               \
    {                                                                          \
      const int sel = ((t) + 1) & 1;                                           \
      const int awin = 176 + sel * 24;                                         \
      _Pragma("unroll")                                                        \
      for (int mt = 0; mt < 2; ++mt) {                                         \
        v8h a_ = *(const v8h*)&sIn[(mt * 16 + nlo) * SIN_STR + awin + q * 8];  \
        v4f z4 = {0.f, 0.f, 0.f, 0.f};                                         \
        gacc[mt] = sel ? mfma16(a_, bGamB, z4) : mfma16(a_, bGamA, z4);        \
      }                                                                        \
    }                                                                          \
    /* ---- wave-local alpha(t) MFMA: window @232, tile mtw, own 8 rows */     \
    {                                                                          \
      v8h a_ = *(const v8h*)&sIn[(mtw * 16 + nlo) * SIN_STR + 232 + q * 8];    \
      v4f z4 = {0.f, 0.f, 0.f, 0.f};                                           \
      v4f aacc = mfma16(a_, bAl, z4);                                          \
      if ((q >> 1) == (wid & 1) && nlo < 9) {                                  \
        _Pragma("unroll")                                                      \
        for (int r = 0; r < 4; ++r)                                            \
          sPk[(mtw * 16 + q * 4 + r) * PK_STR + 27 + nlo] = (hh)aacc[r];       \
      }                                                                        \
    }                                                                          \
    /* ---- wave-local x_h: tile mtw (redundant with pair wave), own rows */   \
    {                                                                          \
      v4f xacc = {0.f, 0.f, 0.f, 0.f};                                         \
      _Pragma("unroll")                                                        \
      for (int kt = 0; kt < 3; ++kt) {                                         \
        v8h a_ = *(const v8h*)&sIn[(mtw * 16 + nlo) * SIN_STR + pb +           \
                                   kt * 32 + q * 8];                           \
        xacc = mfma16(a_, bH[kt], xacc);                                       \
      }                                                                        \
      if ((q >> 1) == (wid & 1) && nlo < 9) {                                  \
        _Pragma("unroll")                                                      \
        for (int r = 0; r < 4; ++r)                                            \
          sPk[(mtw * 16 + q * 4 + r) * PK_STR + 18 + nlo] = (hh)xacc[r];       \
      }                                                                        \
    }                                                                          \
    /* wave-local producer->consumer fence (no cross-wave dependency) */       \
    asm volatile("s_waitcnt lgkmcnt(0)" ::: "memory");                         \
    /* ==== P2: wave-local — x_c, z, c_h, c_c, loss (alpha precomputed) */     \
    {                                                                          \
      const int pk = eP * PK_STR;                                              \
      float x_f  = (float)sPk[pk + fqw];                                       \
      float m_f  = (float)sPk[pk + 9 + fqw];                                   \
      float xh_f = (float)sPk[pk + 18 + fqw];                                  \
      float a1   = (float)sPk[pk + 27 + fqw];                                  \
      v8h r0 = *(const v8h*)&sPk[pk];                                          \
      v8h r1 = *(const v8h*)&sPk[pk + 8];                                      \
      v8h r2 = *(const v8h*)&sPk[pk + 16];                                     \
      v8h r3 = *(const v8h*)&sPk[pk + 24];                                     \
      hh xxh[9] = {r0[0],r0[1],r0[2],r0[3],r0[4],r0[5],r0[6],r0[7],r1[0]};     \
      hh mmh[9] = {r1[1],r1[2],r1[3],r1[4],r1[5],r1[6],r1[7],r2[0],r2[1]};     \
      hh xhh[9] = {r2[2],r2[3],r2[4],r2[5],r2[6],r2[7],r3[0],r3[1],r3[2]};     \
      hh xch[10];                                                              \
      _Pragma("unroll")                                                        \
      for (int f = 0; f < 9; ++f) {                                            \
        u16 mb = __builtin_bit_cast(u16, mmh[f]);                              \
        xch[f] = mb ? xxh[f] : xhh[f];                                         \
      }                                                                        \
      xch[9] = (hh)0.f;                                                        \
      h2 xc2[5] = {mkh2(xch[0],xch[1]), mkh2(xch[2],xch[3]),                   \
                   mkh2(xch[4],xch[5]), mkh2(xch[6],xch[7]),                   \
                   mkh2(xch[8],xch[9])};                                       \
      float z1a = bf1, z1b = 0.f;                                              \
      z1a = fdot2(wf1[0], xc2[0], z1a); z1b = fdot2(wf1[1], xc2[1], z1b);      \
      z1a = fdot2(wf1[2], xc2[2], z1a); z1b = fdot2(wf1[3], xc2[3], z1b);      \
      z1a = fdot2(wf1[4], xc2[4], z1a);                                        \
      float z1 = z1a + z1b;                                                    \
      float ch1 = xh_f + a1 * (z1 - xh_f);                                     \
      bool obs1 = (m_f != 0.f);                                                \
      float cc1 = obs1 ? x_f : ch1;                                            \
      float lterm = obs1 ? (fabsf(x_f - xh_f) + fabsf(x_f - z1) +              \
                            fabsf(x_f - ch1)) : 0.f;                           \
      sIn[eP * SIN_STR + pb + fqw] = (hh)cc1;                                  \
      sIn[eP * SIN_STR + pb + 9 + fqw] = (hh)m_f;                              \
      op1[0] = cc1;                                                            \
      if (fqw == 7) {                                                          \
        float a2 = (float)sPk[pk + 27 + 8];                                    \
        float z2a = bf2, z2b = 0.f;                                            \
        z2a = fdot2(wf2[0], xc2[0], z2a); z2b = fdot2(wf2[1], xc2[1], z2b);    \
        z2a = fdot2(wf2[2], xc2[2], z2a); z2b = fdot2(wf2[3], xc2[3], z2b);    \
        z2a = fdot2(wf2[4], xc2[4], z2a);                                      \
        float z2 = z2a + z2b;                                                  \
        float x8 = (float)xxh[8], m8 = (float)mmh[8], xh8 = (float)xhh[8];     \
        float ch2 = xh8 + a2 * (z2 - xh8);                                     \
        bool obs2 = (m8 != 0.f);                                               \
        float cc2 = obs2 ? x8 : ch2;                                           \
        lterm += obs2 ? (fabsf(x8 - xh8) + fabsf(x8 - z2) +                    \
                         fabsf(x8 - ch2)) : 0.f;                               \
        sIn[eP * SIN_STR + pb + 8] = (hh)cc2;                                  \
        sIn[eP * SIN_STR + pb + 17] = mmh[8];                                  \
        op1[1] = cc2;                                                          \
      }                                                                        \
      loss_acc += lterm * inv_den;                                             \
      op1 += FEAT;                                                             \
    }                                                                          \
    BARX();                                                                    \
    /* ==== Phase B: issue next loads, gates MFMA, LSTM, publish h, commit */  \
    {                                                                          \
      const bool ldN = ((t) + 2 < T_STEPS);                                    \
      const bool ldD = ((t) + 3 < T_STEPS);                                    \
      if (ldN) {                                                               \
        size_t offn = (size_t)(b0 + e1) * (T_STEPS * FEAT) +                   \
                      ((t) + 2) * FEAT + f1;                                   \
        pxN = values[offn]; pmN = masks[offn];                                 \
        if (tid < 32) {                                                        \
          size_t offn2 = (size_t)(b0 + e2g) * (T_STEPS * FEAT) +               \
                         ((t) + 2) * FEAT + f2g;                               \
          pxNb = values[offn2]; pmNb = masks[offn2];                           \
        }                                                                      \
      }                                                                        \
      if (ldD) {                                                               \
        size_t offd = (size_t)(b0 + e1) * (T_STEPS * FEAT) +                   \
                      ((t) + 3) * FEAT + f1;                                   \
        pdN = deltas[offd];                                                    \
        if (tid < 32) {                                                        \
          size_t offd2 = (size_t)(b0 + e2g) * (T_STEPS * FEAT) +               \
                         ((t) + 3) * FEAT + f2g;                               \
          pdNb = deltas[offd2];                                                \
        }                                                                      \
      }                                                                        \
      const int pub = (((t) + 1) & 1) * 96;                                    \
      v8h af[2][3];                                                            \
      _Pragma("unroll")                                                        \
      for (int mt = 0; mt < 2; ++mt)                                           \
        _Pragma("unroll")                                                      \
        for (int kt = 0; kt < 3; ++kt)                                         \
          af[mt][kt] = *(const v8h*)&sIn[(mt * 16 + nlo) * SIN_STR + pb +      \
                                         kt * 32 + q * 8];                     \
      v4f acc[2][4];                                                           \
      _Pragma("unroll")                                                        \
      for (int mt = 0; mt < 2; ++mt)                                           \
        _Pragma("unroll")                                                      \
        for (int p = 0; p < 4; ++p)                                            \
          acc[mt][p] = (v4f){0.f, 0.f, 0.f, 0.f};                              \
      _Pragma("unroll")                                                        \
      for (int mt = 0; mt < 2; ++mt)                                           \
        _Pragma("unroll")                                                      \
        for (int p = 0; p < 4; ++p)                                            \
          _Pragma("unroll")                                                    \
          for (int kt = 0; kt < 3; ++kt)                                       \
            acc[mt][p] = mfma16(af[mt][kt], bG[p][kt], acc[mt][p]);            \
      _Pragma("unroll")                                                        \
      for (int mt = 0; mt < 2; ++mt) {                                         \
        _Pragma("unroll")                                                      \
        for (int r = 0; r < 4; ++r) {                                          \
          float ig = sigmoid_fast(acc[mt][0][r]);                              \
          float fg = sigmoid_fast(acc[mt][1][r]);                              \
          float gg = tanh_fast(acc[mt][2][r]);                                 \
          float og = sigmoid_fast(acc[mt][3][r]);                              \
          float cn = fg * c_s[mt * 4 + r] + ig * gg;                           \
          c_s[mt * 4 + r] = cn;                                                \
          float hn = og * tanh_fast(cn);                                       \
          float gam = fast_exp2(fmaxf(gacc[mt][r], 0.f) * -1.442695041f);      \
          sIn[(mt * 16 + q * 4 + r) * SIN_STR + pub + 18 + j_col] =            \
              (hh)(hn * gam);                                                  \
        }                                                                      \
      }                                                                        \
      if ((t) + 1 < T_STEPS) {                                                 \
        sPk[e1 * PK_STR + f1] = (hh)pxC;                                       \
        sPk[e1 * PK_STR + 9 + f1] = (hh)pmC;                                   \
        sIn[e1 * SIN_STR + 233 + f1] =                                         \
            (hh)fast_exp2(fmaxf(dH * wgx1 + bgx1, 0.f) * -1.442695041f);       \
        sIn[e1 * SIN_STR + 242 + f1] = (hh)pmC;                                \
        if (tid < 32) {                                                        \
          sPk[e2g * PK_STR + f2g] = (hh)pxCb;                                  \
          sPk[e2g * PK_STR + 9 + f2g] = (hh)pmCb;                              \
          sIn[e2g * SIN_STR + 233 + f2g] =                                     \
              (hh)fast_exp2(fmaxf(dHb * wgx2 + bgx2, 0.f) * -1.442695041f);    \
          sIn[e2g * SIN_STR + 242 + f2g] = (hh)pmCb;                           \
        }                                                                      \
      }                                                                        \
      if ((t) + 2 < T_STEPS) {                                                 \
        const int sb = 192 + ((t) & 1) * 10;                                   \
        sIn[e1 * SIN_STR + sb + f1] = (hh)pdC;                                 \
        if (tid < 32) sIn[e2g * SIN_STR + sb + f2g] = (hh)pdCb;                \
      }                                                                        \
      dH = pdC; dHb = pdCb;                                                    \
    }                                                                          \
    BARX();                                                                    \
  }

// ---------------- kernel 2: the full RITS scan ------------------------------
__global__ __launch_bounds__(256, 2) void rits_kernel(
    const float* __restrict__ values, const float* __restrict__ masks,
    const float* __restrict__ deltas,
    const float* __restrict__ W_gh, const float* __restrict__ b_gh,
    const float* __restrict__ W_gx, const float* __restrict__ b_gx,
    const float* __restrict__ W_hist, const float* __restrict__ b_hist,
    const float* __restrict__ W_feat, const float* __restrict__ b_feat,
    const float* __restrict__ W_comb, const float* __restrict__ b_comb,
    const float* __restrict__ W_ih, const float* __restrict__ W_hh,
    const float* __restrict__ b_ih, const float* __restrict__ b_hh,
    const float* __restrict__ denom, float* __restrict__ out) {

  __shared__ __align__(16) hh sIn[BT * SIN_STR];   // 16896 B
  __shared__ __align__(16) hh sPk[BT * PK_STR];    //  2560 B
  __shared__ float sRed[256];

  const int tid = threadIdx.x;
  const int lane = tid & 63;
  const int wid = tid >> 6;
  const int q = lane >> 4;
  const int nlo = lane & 15;
  const int b0 = blockIdx.x * BT;
  const int j_col = 16 * wid + nlo;
  const int mtw = wid >> 1;          // 16-row tile containing this wave's elems

  // ---- persistent register B-fragments (k = q*8+jj relative to window) ----
  v8h bG[4][3];        // gates: window = parity block, k0..17 Wih, 18..81 Whh, 82 bias
#pragma unroll
  for (int p = 0; p < 4; ++p)
#pragma unroll
    for (int kt = 0; kt < 3; ++kt) {
      int n = 64 * p + j_col;
      v8h r;
#pragma unroll
      for (int jj = 0; jj < 8; ++jj) {
        int k = kt * 32 + q * 8 + jj;
        float v = 0.f;
        if (k < 18)       v = W_ih[n * 18 + k];
        else if (k < 82)  v = W_hh[n * 64 + (k - 18)];
        else if (k == 82) v = b_ih[n] + b_hh[n];
        r[jj] = (hh)v;
      }
      bG[p][kt] = r;
    }
  v8h bH[3];           // x_h: cols nlo<9, k 18..81 Whist, 82 bias
#pragma unroll
  for (int kt = 0; kt < 3; ++kt) {
    v8h r;
#pragma unroll
    for (int jj = 0; jj < 8; ++jj) {
      int k = kt * 32 + q * 8 + jj;
      float v = 0.f;
      if (nlo < 9) {
        if (k >= 18 && k < 82) v = W_hist[nlo * 64 + (k - 18)];
        else if (k == 82)      v = b_hist[nlo];
      }
      r[jj] = (hh)v;
    }
    bH[kt] = r;
  }
  // gamma_h windows: A @176 (k2='1'@178 -> b_gh, k16..24 = dA); B @200 (k2..10 = dB, k12='1'@212)
  v8h bGamA, bGamB;
  {
    int n = j_col;
    v8h ra, rb;
#pragma unroll
    for (int jj = 0; jj < 8; ++jj) {
      int k = q * 8 + jj;
      float va = 0.f, vb = 0.f;
      if (k == 2) va = b_gh[n];
      else if (k >= 16 && k < 25) va = W_gh[n * 9 + (k - 16)];
      if (k >= 2 && k < 11) vb = W_gh[n * 9 + (k - 2)];
      else if (k == 12) vb = b_gh[n];
      ra[jj] = (hh)va; rb[jj] = (hh)vb;
    }
    bGamA = ra; bGamB = rb;
  }
  // alpha window fragment: k0 -> b_comb (hits the '1' @232), k1..9 -> W_comb
  // gx-part, k10..18 -> W_comb m-part; cols nlo<9.
  v8h bAl;
  {
    v8h r;
#pragma unroll
    for (int jj = 0; jj < 8; ++jj) {
      int k = q * 8 + jj;
      float v = 0.f;
      if (nlo < 9) {
        if (k == 0)       v = b_comb[nlo];
        else if (k < 10)  v = W_comb[nlo * 18 + (k - 1)];
        else if (k < 19)  v = W_comb[nlo * 18 + 9 + (k - 10)];
      }
      r[jj] = (hh)v;
    }
    bAl = r;
  }

  // ---- per-lane P2 weights (runtime row fq baked into registers) ----
  const int eP = tid >> 3, fqw = tid & 7;
  h2 wf1[5], wf2[5];
  float bf1 = b_feat[fqw], bf2 = b_feat[8];
#pragma unroll
  for (int j = 0; j < 5; ++j) {
    int i0 = 2 * j, i1 = 2 * j + 1;
    hh a0 = (hh)((i0 == fqw) ? 0.f : W_feat[fqw * 9 + i0]);
    hh a1 = (hh)((i1 < 9) ? ((i1 == fqw) ? 0.f : W_feat[fqw * 9 + i1]) : 0.f);
    wf1[j] = mkh2(a0, a1);
    hh c0 = (hh)((i0 == 8) ? 0.f : W_feat[8 * 9 + i0]);
    hh c1 = (hh)((i1 < 9) ? W_feat[8 * 9 + i1] : 0.f);
    wf2[j] = mkh2(c0, c1);
  }

  // ---- loader thread mapping + per-loader gamma_x weights ----
  const int e1 = tid / 9, f1 = tid - 9 * e1;
  const int e2g = (tid + 256) / 9, f2g = (tid + 256) - 9 * e2g;
  const float wgx1 = W_gx[f1 * 9 + f1], bgx1 = b_gx[f1];
  float wgx2 = 0.f, bgx2 = 0.f;
  if (tid < 32) { wgx2 = W_gx[f2g * 9 + f2g]; bgx2 = b_gx[f2g]; }

  // ---- per-thread output pointer (advances FEAT floats per step) ----
  float* op1 = out + 1 + (size_t)(b0 + eP) * (T_STEPS * FEAT) + fqw;

  // ---- LDS init ----
  for (int i = tid; i < BT * SIN_STR; i += 256) sIn[i] = (hh)0.f;
  __syncthreads();
  if (tid < BT) {
    sIn[tid * SIN_STR + 82] = (hh)1.f;
    sIn[tid * SIN_STR + 178] = (hh)1.f;
    sIn[tid * SIN_STR + 212] = (hh)1.f;
    sIn[tid * SIN_STR + 232] = (hh)1.f;   // alpha-window bias one
  }
  // prefetch register sets (A/B alternate per step parity)
  float pA_x = 0.f, pA_m = 0.f, pA_d = 0.f, pA_xb = 0.f, pA_mb = 0.f, pA_db = 0.f;
  float pB_x = 0.f, pB_m = 0.f, pB_d = 0.f, pB_xb = 0.f, pB_mb = 0.f, pB_db = 0.f;
  float dH = 0.f, dHb = 0.f;    // deltas(t+1) for the gx commit at PhaseB(t)
  {
    size_t off = (size_t)(b0 + e1) * (T_STEPS * FEAT) + f1;
    float d0 = deltas[off];
    float m0 = masks[off];
    sPk[e1 * PK_STR + f1] = (hh)values[off];
    sPk[e1 * PK_STR + 9 + f1] = (hh)m0;
    sIn[e1 * SIN_STR + 233 + f1] =
        (hh)fast_exp2(fmaxf(d0 * wgx1 + bgx1, 0.f) * -1.442695041f);
    sIn[e1 * SIN_STR + 242 + f1] = (hh)m0;
    float d1 = deltas[off + FEAT];
    dH = d1;
    sIn[e1 * SIN_STR + 202 + f1] = (hh)d1;    // d(1) -> dB (parity 1)
    pA_x = values[off + FEAT]; pA_m = masks[off + FEAT];   // t=1 data
    pA_d = deltas[off + 2 * FEAT];                         // d(2)
    if (tid < 32) {
      size_t off2 = (size_t)(b0 + e2g) * (T_STEPS * FEAT) + f2g;
      float d0b = deltas[off2];
      float m0b = masks[off2];
      sPk[e2g * PK_STR + f2g] = (hh)values[off2];
      sPk[e2g * PK_STR + 9 + f2g] = (hh)m0b;
      sIn[e2g * SIN_STR + 233 + f2g] =
          (hh)fast_exp2(fmaxf(d0b * wgx2 + bgx2, 0.f) * -1.442695041f);
      sIn[e2g * SIN_STR + 242 + f2g] = (hh)m0b;
      float d1b = deltas[off2 + FEAT];
      dHb = d1b;
      sIn[e2g * SIN_STR + 202 + f2g] = (hh)d1b;
      pA_xb = values[off2 + FEAT]; pA_mb = masks[off2 + FEAT];
      pA_db = deltas[off2 + 2 * FEAT];
    }
  }
  __syncthreads();

  float c_s[8];
#pragma unroll
  for (int i = 0; i < 8; ++i) c_s[i] = 0.f;
  float loss_acc = 0.f;

  for (int t = 0; t < T_STEPS; t += 2) {
    RITS_STEP(t,     pA_x, pA_m, pA_d, pA_xb, pA_mb, pA_db,
                     pB_x, pB_m, pB_d, pB_xb, pB_mb, pB_db);
    RITS_STEP(t + 1, pB_x, pB_m, pB_d, pB_xb, pB_mb, pB_db,
                     pA_x, pA_m, pA_d, pA_xb, pA_mb, pA_db);
  }

  // ---- loss reduction ----
  sRed[tid] = loss_acc;
  __syncthreads();
  for (int k = 128; k > 0; k >>= 1) {
    if (tid < k) sRed[tid] += sRed[tid + k];
    __syncthreads();
  }
  if (tid == 0) atomicAdd(out, sRed[0] * (1.f / (float)T_STEPS));
}

extern "C" void kernel_launch(void* const* d_in, const int* in_sizes, int n_in,
                              void* d_out, int out_size, void* d_ws, size_t ws_size,
                              hipStream_t stream) {
  const float* values = (const float*)d_in[0];
  const float* masks  = (const float*)d_in[1];
  const float* deltas = (const float*)d_in[2];
  const float* W_gh   = (const float*)d_in[3];
  const float* b_gh   = (const float*)d_in[4];
  const float* W_gx   = (const float*)d_in[5];
  const float* b_gx   = (const float*)d_in[6];
  const float* W_hist = (const float*)d_in[7];
  const float* b_hist = (const float*)d_in[8];
  const float* W_feat = (const float*)d_in[9];
  const float* b_feat = (const float*)d_in[10];
  const float* W_comb = (const float*)d_in[11];
  const float* b_comb = (const float*)d_in[12];
  const float* W_ih   = (const float*)d_in[13];
  const float* W_hh   = (const float*)d_in[14];
  const float* b_ih   = (const float*)d_in[15];
  const float* b_hh   = (const float*)d_in[16];

  float* out = (float*)d_out;
  float* ws  = (float*)d_ws;
  int B = in_sizes[0] / (T_STEPS * FEAT);
  int nb1 = (B * 9) / 256;

  size_t need = (size_t)(64 + (size_t)nb1 * T_STEPS) * sizeof(float);
  if (ws_size >= need) {
    denom_part<<<nb1, 256, 0, stream>>>(masks, ws);
    denom_final<<<1, 576, 0, stream>>>(ws, out, nb1);
  } else {
    zero_ws<<<1, 64, 0, stream>>>(ws, out);
    denom_kernel<<<nb1, 256, 0, stream>>>(masks, ws);
  }
  rits_kernel<<<B / BT, 256, 0, stream>>>(values, masks, deltas,
                                          W_gh, b_gh, W_gx, b_gx,
                                          W_hist, b_hist, W_feat, b_feat,
                                          W_comb, b_comb, W_ih, W_hh,
                                          b_ih, b_hh, ws, out);
}